// Round 3
// baseline (278.576 us; speedup 1.0000x reference)
//
#include <hip/hip_runtime.h>

#define N_NODES 50000
#define N_EDGES 800000
#define F_IN    512
#define H_DIM   256
#define C_DIM   64
#define MPAD    50048   // 391 * 128

typedef __bf16 bf16;
typedef __bf16 bf16x4 __attribute__((ext_vector_type(4)));
typedef __bf16 bf16x8 __attribute__((ext_vector_type(8)));
typedef float  f32x4  __attribute__((ext_vector_type(4)));
typedef int    i32x4  __attribute__((ext_vector_type(4)));
typedef unsigned int u32;

__device__ __forceinline__ void gl_lds16(const void* g, void* l) {
    __builtin_amdgcn_global_load_lds(
        (const __attribute__((address_space(1))) u32*)g,
        (__attribute__((address_space(3))) u32*)l, 16, 0, 0);
}

__device__ __forceinline__ float unpack_val(u32 pk) {
    return __builtin_bit_cast(float, pk << 16);
}

// ---------------- edge sort (counting sort by destination row) ----------------

__global__ __launch_bounds__(256) void hist_k(const int* __restrict__ rows,
                                              int* __restrict__ cnt) {
    int e = blockIdx.x * 256 + threadIdx.x;
    atomicAdd(&cnt[rows[e]], 1);
}

// multi-block scan: 49 blocks x 256 threads, 4 elems/thread (1024/block)
__global__ __launch_bounds__(256) void scan1_k(const int* __restrict__ cnt,
                                               int* __restrict__ starts,
                                               int* __restrict__ bsum) {
    __shared__ int wtot[4];
    int tid = threadIdx.x, wid = tid >> 6, lane = tid & 63;
    int base = blockIdx.x * 1024 + tid * 4;
    i32x4 v = (i32x4){0, 0, 0, 0};
    if (base < N_NODES) v = *(const i32x4*)(cnt + base);
    int t = v[0] + v[1] + v[2] + v[3];
    int incl = t;
#pragma unroll
    for (int off = 1; off < 64; off <<= 1) {
        int u = __shfl_up(incl, off, 64);
        if (lane >= off) incl += u;
    }
    if (lane == 63) wtot[wid] = incl;
    __syncthreads();
    int wpre = 0;
#pragma unroll
    for (int w = 0; w < 4; w++)
        if (w < wid) wpre += wtot[w];
    int excl = wpre + incl - t;
    if (base < N_NODES) {
        i32x4 o;
        o[0] = excl;
        o[1] = excl + v[0];
        o[2] = excl + v[0] + v[1];
        o[3] = excl + v[0] + v[1] + v[2];
        *(i32x4*)(starts + base) = o;
    }
    if (tid == 255) bsum[blockIdx.x] = wpre + incl;
}

__global__ __launch_bounds__(64) void scan2_k(int* __restrict__ bsum,
                                              int* __restrict__ boff) {
    int lane = threadIdx.x;
    int v = (lane < 49) ? bsum[lane] : 0;
    int incl = v;
#pragma unroll
    for (int off = 1; off < 64; off <<= 1) {
        int u = __shfl_up(incl, off, 64);
        if (lane >= off) incl += u;
    }
    if (lane < 49) boff[lane] = incl - v;
}

__global__ __launch_bounds__(256) void scan3_k(int* __restrict__ starts,
                                               const int* __restrict__ boff,
                                               int* __restrict__ cursor) {
    int i = blockIdx.x * 1024 + threadIdx.x * 4;
    int off = boff[blockIdx.x];
    if (i < N_NODES) {
        i32x4 s = *(const i32x4*)(starts + i);
        s[0] += off; s[1] += off; s[2] += off; s[3] += off;
        *(i32x4*)(starts + i) = s;
        *(i32x4*)(cursor + i) = s;
    }
    if (blockIdx.x == 0 && threadIdx.x == 0) starts[N_NODES] = N_EDGES;
}

// scatter: single 4B packed write per edge (col<<16 | bf16(val))
__global__ __launch_bounds__(256) void scatter_k(const int* __restrict__ rows,
                                                 const int* __restrict__ cols,
                                                 const float* __restrict__ vals,
                                                 int* __restrict__ cursor,
                                                 u32* __restrict__ epack) {
    int e = blockIdx.x * 256 + threadIdx.x;
    int r = rows[e];
    unsigned short vb = __builtin_bit_cast(unsigned short, (bf16)vals[e]);
    u32 pk = ((u32)cols[e] << 16) | (u32)vb;
    int p = atomicAdd(&cursor[r], 1);
    epack[p] = pk;
}

// ---------------- dtype prep ----------------

__global__ __launch_bounds__(256) void cvt_nf_k(const float* __restrict__ nf,
                                                bf16* __restrict__ a16) {
    size_t gid = (size_t)blockIdx.x * 256 + threadIdx.x;
    const f32x4* s = (const f32x4*)nf;
    f32x4 u = s[gid * 2], v = s[gid * 2 + 1];
    bf16x8 o;
    o[0] = (bf16)u[0]; o[1] = (bf16)u[1]; o[2] = (bf16)u[2]; o[3] = (bf16)u[3];
    o[4] = (bf16)v[0]; o[5] = (bf16)v[1]; o[6] = (bf16)v[2]; o[7] = (bf16)v[3];
    *(bf16x8*)(a16 + gid * 8) = o;
}

__global__ __launch_bounds__(256) void tr_w1_k(const float* __restrict__ W,
                                               bf16* __restrict__ Wt) {
    int i = blockIdx.x * 256 + threadIdx.x;
    int k = i >> 8, n = i & 255;
    Wt[n * F_IN + k] = (bf16)W[i];
}

__global__ __launch_bounds__(256) void tr_w2_k(const float* __restrict__ W,
                                               bf16* __restrict__ Wt) {
    int i = blockIdx.x * 256 + threadIdx.x;
    int k = i >> 6, n = i & 63;
    Wt[n * H_DIM + k] = (bf16)W[i];
}

// ---------------- bf16 MFMA GEMM: C[M,N] = A[M,K] @ Bt[N,K]^T + bias ----------------

template <int BN, bool BF16OUT>
__global__ __launch_bounds__(256) void gemm_k(const bf16* __restrict__ A,
                                              const bf16* __restrict__ Bt,
                                              const float* __restrict__ bias,
                                              void* __restrict__ C,
                                              int M, int K, int Nc) {
    constexpr int BM = 128, BK = 64;
    constexpr int NFRAG = BN / 32;
    constexpr int A_ISS = (BM * BK * 2) / 4096;
    constexpr int B_ISS = (BN * BK * 2) / 4096;
    __shared__ bf16 As[BM * BK];
    __shared__ bf16 Bs[BN * BK];

    int tid = threadIdx.x;
    int wid = tid >> 6, lane = tid & 63;
    int wr = wid >> 1, wc = wid & 1;
    int bm = blockIdx.x, bn = blockIdx.y;

    f32x4 acc[4][NFRAG];
#pragma unroll
    for (int m = 0; m < 4; m++)
#pragma unroll
        for (int n = 0; n < NFRAG; n++) acc[m][n] = (f32x4){0.f, 0.f, 0.f, 0.f};

    for (int kt = 0; kt < K; kt += BK) {
#pragma unroll
        for (int j = 0; j < A_ISS; j++) {
            int chunk = j * 256 + tid;
            int row = chunk >> 3, kc = chunk & 7;
            gl_lds16(A + (size_t)(bm * BM + row) * K + kt + kc * 8,
                     &As[(j * 256 + wid * 64) * 8]);
        }
#pragma unroll
        for (int j = 0; j < B_ISS; j++) {
            int chunk = j * 256 + tid;
            int row = chunk >> 3, kc = chunk & 7;
            gl_lds16(Bt + (size_t)(bn * BN + row) * K + kt + kc * 8,
                     &Bs[(j * 256 + wid * 64) * 8]);
        }
        __syncthreads();

        bf16x8 afr[2][4], bfr[2][NFRAG];
#pragma unroll
        for (int kk = 0; kk < 2; kk++) {
#pragma unroll
            for (int m = 0; m < 4; m++)
                afr[kk][m] = *(const bf16x8*)&As[(wr * 64 + m * 16 + (lane & 15)) * BK +
                                                 kk * 32 + (lane >> 4) * 8];
#pragma unroll
            for (int n = 0; n < NFRAG; n++)
                bfr[kk][n] = *(const bf16x8*)&Bs[(wc * (BN / 2) + n * 16 + (lane & 15)) * BK +
                                                 kk * 32 + (lane >> 4) * 8];
        }
#pragma unroll
        for (int kk = 0; kk < 2; kk++)
#pragma unroll
            for (int m = 0; m < 4; m++)
#pragma unroll
                for (int n = 0; n < NFRAG; n++)
                    acc[m][n] = __builtin_amdgcn_mfma_f32_16x16x32_bf16(
                        afr[kk][m], bfr[kk][n], acc[m][n], 0, 0, 0);
        __syncthreads();
    }

#pragma unroll
    for (int m = 0; m < 4; m++) {
        int row0 = bm * BM + wr * 64 + m * 16 + (lane >> 4) * 4;
#pragma unroll
        for (int n = 0; n < NFRAG; n++) {
            int col = bn * BN + wc * (BN / 2) + n * 16 + (lane & 15);
            float bz = bias[col];
#pragma unroll
            for (int r = 0; r < 4; r++) {
                int row = row0 + r;
                if (row < M) {
                    float v = acc[m][n][r] + bz;
                    if constexpr (BF16OUT)
                        ((bf16*)C)[(size_t)row * Nc + col] = (bf16)v;
                    else
                        ((float*)C)[(size_t)row * Nc + col] = v;
                }
            }
        }
    }
}

// ---------------- SpMM1: x[i,:] = relu(sum val * s1[col,:]), D=256, bf16, unroll 4 ----------------

__global__ __launch_bounds__(256) void spmm1_k(const int* __restrict__ starts,
                                               const u32* __restrict__ epack,
                                               const bf16* __restrict__ s1,
                                               bf16* __restrict__ x16) {
    int wid = threadIdx.x >> 6, lane = threadIdx.x & 63;
    int row = blockIdx.x * 4 + wid;
    if (row >= N_NODES) return;
    int s = starts[row], e = starts[row + 1];
    f32x4 acc = (f32x4){0.f, 0.f, 0.f, 0.f};
    int p = s;
    for (; p + 4 <= e; p += 4) {
        u32 k0 = epack[p], k1 = epack[p + 1], k2 = epack[p + 2], k3 = epack[p + 3];
        float v0 = unpack_val(k0), v1 = unpack_val(k1),
              v2 = unpack_val(k2), v3 = unpack_val(k3);
        bf16x4 g0 = *(const bf16x4*)(s1 + (size_t)(k0 >> 16) * H_DIM + lane * 4);
        bf16x4 g1 = *(const bf16x4*)(s1 + (size_t)(k1 >> 16) * H_DIM + lane * 4);
        bf16x4 g2 = *(const bf16x4*)(s1 + (size_t)(k2 >> 16) * H_DIM + lane * 4);
        bf16x4 g3 = *(const bf16x4*)(s1 + (size_t)(k3 >> 16) * H_DIM + lane * 4);
#pragma unroll
        for (int j = 0; j < 4; j++)
            acc[j] += v0 * (float)g0[j] + v1 * (float)g1[j] +
                      v2 * (float)g2[j] + v3 * (float)g3[j];
    }
    for (; p < e; ++p) {
        u32 k = epack[p];
        float v = unpack_val(k);
        bf16x4 g = *(const bf16x4*)(s1 + (size_t)(k >> 16) * H_DIM + lane * 4);
#pragma unroll
        for (int j = 0; j < 4; j++) acc[j] += v * (float)g[j];
    }
    bf16x4 o;
#pragma unroll
    for (int j = 0; j < 4; j++) o[j] = (bf16)fmaxf(acc[j], 0.f);
    *(bf16x4*)(x16 + (size_t)row * H_DIM + lane * 4) = o;
}

// ---------------- SpMM2 + log_softmax fused: D=64, lane = class, unroll 4 ----------------

__global__ __launch_bounds__(256) void spmm2_sm_k(const int* __restrict__ starts,
                                                  const u32* __restrict__ epack,
                                                  const float* __restrict__ s2,
                                                  float* __restrict__ out) {
    int wid = threadIdx.x >> 6, lane = threadIdx.x & 63;
    int row = blockIdx.x * 4 + wid;
    if (row >= N_NODES) return;
    int s = starts[row], e = starts[row + 1];
    float acc = 0.f;
    int p = s;
    for (; p + 4 <= e; p += 4) {
        u32 k0 = epack[p], k1 = epack[p + 1], k2 = epack[p + 2], k3 = epack[p + 3];
        float g0 = s2[(size_t)(k0 >> 16) * C_DIM + lane];
        float g1 = s2[(size_t)(k1 >> 16) * C_DIM + lane];
        float g2 = s2[(size_t)(k2 >> 16) * C_DIM + lane];
        float g3 = s2[(size_t)(k3 >> 16) * C_DIM + lane];
        acc += unpack_val(k0) * g0 + unpack_val(k1) * g1 +
               unpack_val(k2) * g2 + unpack_val(k3) * g3;
    }
    for (; p < e; ++p) {
        u32 k = epack[p];
        acc += unpack_val(k) * s2[(size_t)(k >> 16) * C_DIM + lane];
    }
    float mx = acc;
#pragma unroll
    for (int off = 32; off >= 1; off >>= 1) mx = fmaxf(mx, __shfl_xor(mx, off, 64));
    float ex = expf(acc - mx);
    float se = ex;
#pragma unroll
    for (int off = 32; off >= 1; off >>= 1) se += __shfl_xor(se, off, 64);
    out[(size_t)row * C_DIM + lane] = (acc - mx) - logf(se);
}

// ---------------- launch ----------------

extern "C" void kernel_launch(void* const* d_in, const int* in_sizes, int n_in,
                              void* d_out, int out_size, void* d_ws, size_t ws_size,
                              hipStream_t stream) {
    const float* nf   = (const float*)d_in[0];
    const int*   rows = (const int*)d_in[1];
    const int*   cols = (const int*)d_in[2];
    const float* vals = (const float*)d_in[3];
    const float* W1   = (const float*)d_in[4];
    const float* b1   = (const float*)d_in[5];
    const float* W2   = (const float*)d_in[6];
    const float* b2   = (const float*)d_in[7];
    float* out = (float*)d_out;

    char* w = (char*)d_ws;
    auto alloc = [&](size_t b) { void* p = (void*)w; w += (b + 255) & ~(size_t)255; return p; };

    bf16* A16 = (bf16*)alloc((size_t)MPAD * F_IN * 2);
    bf16* x16 = A16;
    bf16*  sup1 = (bf16*)alloc((size_t)N_NODES * H_DIM * 2);
    float* sup2 = (float*)sup1;
    bf16* W1t = (bf16*)alloc((size_t)H_DIM * F_IN * 2);
    bf16* W2t = (bf16*)alloc((size_t)C_DIM * H_DIM * 2);
    int* cnt    = (int*)alloc((size_t)N_NODES * 4);
    int* starts = (int*)alloc((size_t)(N_NODES + 1) * 4);
    int* cursor = (int*)alloc((size_t)N_NODES * 4);
    int* bsum   = (int*)alloc(64 * 4);
    int* boff   = (int*)alloc(64 * 4);
    u32* epack  = (u32*)alloc((size_t)N_EDGES * 4);

    // edge sort
    hipMemsetAsync(cnt, 0, (size_t)N_NODES * 4, stream);
    hist_k<<<N_EDGES / 256, 256, 0, stream>>>(rows, cnt);
    scan1_k<<<49, 256, 0, stream>>>(cnt, starts, bsum);
    scan2_k<<<1, 64, 0, stream>>>(bsum, boff);
    scan3_k<<<49, 256, 0, stream>>>(starts, boff, cursor);
    scatter_k<<<N_EDGES / 256, 256, 0, stream>>>(rows, cols, vals, cursor, epack);

    // dtype prep
    cvt_nf_k<<<(N_NODES * F_IN / 8) / 256, 256, 0, stream>>>(nf, A16);
    tr_w1_k<<<(F_IN * H_DIM) / 256, 256, 0, stream>>>(W1, W1t);
    tr_w2_k<<<(H_DIM * C_DIM) / 256, 256, 0, stream>>>(W2, W2t);

    // layer 1
    gemm_k<128, true><<<dim3(MPAD / 128, H_DIM / 128), 256, 0, stream>>>(
        A16, W1t, b1, (void*)sup1, N_NODES, F_IN, H_DIM);
    spmm1_k<<<(N_NODES + 3) / 4, 256, 0, stream>>>(starts, epack, sup1, x16);

    // layer 2 + softmax
    gemm_k<64, false><<<dim3(MPAD / 128, 1), 256, 0, stream>>>(
        x16, W2t, b2, (void*)sup2, N_NODES, H_DIM, C_DIM);
    spmm2_sm_k<<<(N_NODES + 3) / 4, 256, 0, stream>>>(starts, epack, sup2, out);

    (void)in_sizes; (void)n_in; (void)out_size; (void)ws_size;
}

// Round 4
// 223.795 us; speedup vs baseline: 1.2448x; 1.2448x over previous
//
#include <hip/hip_runtime.h>

#define N_NODES 50000
#define N_EDGES 800000
#define F_IN    512
#define H_DIM   256
#define C_DIM   64
#define MPAD    50048   // 391 * 128

// sort geometry: bucket = row >> 8 (256 rows/bucket), chunk = 16384 edges
#define NB      196     // ceil(50000/256)
#define NCHUNK  49      // ceil(800000/16384)
#define CHUNK   16384
#define BCAP    6144    // LDS capacity per bucket (mean 4082, +32 sigma)

typedef __bf16 bf16;
typedef __bf16 bf16x4 __attribute__((ext_vector_type(4)));
typedef __bf16 bf16x8 __attribute__((ext_vector_type(8)));
typedef float  f32x4  __attribute__((ext_vector_type(4)));
typedef unsigned int u32;
typedef unsigned char u8;

__device__ __forceinline__ void gl_lds16(const void* g, void* l) {
    __builtin_amdgcn_global_load_lds(
        (const __attribute__((address_space(1))) u32*)g,
        (__attribute__((address_space(3))) u32*)l, 16, 0, 0);
}

__device__ __forceinline__ float unpack_val(u32 pk) {
    return __builtin_bit_cast(float, pk << 16);
}

// ---------------- edge sort: two-level counting sort, coalesced writes ----------------

// k1: per-chunk histogram over NB buckets -> G[bucket*NCHUNK + chunk]
__global__ __launch_bounds__(1024) void histA_k(const int* __restrict__ rows,
                                                u32* __restrict__ G) {
    __shared__ u32 h[16 * NB];
    int tid = threadIdx.x, wid = tid >> 6;
    for (int i = tid; i < 16 * NB; i += 1024) h[i] = 0;
    __syncthreads();
    int base = blockIdx.x * CHUNK;
    int end = base + CHUNK; if (end > N_EDGES) end = N_EDGES;
    for (int e = base + tid; e < end; e += 1024)
        atomicAdd(&h[wid * NB + (rows[e] >> 8)], 1);
    __syncthreads();
    if (tid < NB) {
        u32 s = 0;
#pragma unroll
        for (int w = 0; w < 16; w++) s += h[w * NB + tid];
        G[tid * NCHUNK + blockIdx.x] = s;
    }
}

// k2a: bucket totals -> exclusive scan -> bbase[NB+1]; also starts[N]=E
__global__ __launch_bounds__(256) void bucket_scan_k(const u32* __restrict__ G,
                                                     u32* __restrict__ bbase,
                                                     int* __restrict__ starts) {
    __shared__ u32 wtot[4];
    int tid = threadIdx.x, wid = tid >> 6, lane = tid & 63;
    u32 tot = 0;
    if (tid < NB) {
#pragma unroll
        for (int c = 0; c < NCHUNK; c++) tot += G[tid * NCHUNK + c];
    }
    u32 incl = tot;
#pragma unroll
    for (int off = 1; off < 64; off <<= 1) {
        u32 u = __shfl_up(incl, off, 64);
        if (lane >= off) incl += u;
    }
    if (lane == 63) wtot[wid] = incl;
    __syncthreads();
    u32 wpre = 0;
#pragma unroll
    for (int w = 0; w < 4; w++)
        if (w < wid) wpre += wtot[w];
    if (tid < NB) bbase[tid] = wpre + incl - tot;
    if (tid == 0) { bbase[NB] = N_EDGES; starts[N_NODES] = N_EDGES; }
}

// k2b: per-bucket exclusive scan over chunks; G[b][c] becomes global write offset
__global__ __launch_bounds__(64) void chunk_scan_k(u32* __restrict__ G,
                                                   const u32* __restrict__ bbase) {
    int b = blockIdx.x, lane = threadIdx.x;
    u32 v = (lane < NCHUNK) ? G[b * NCHUNK + lane] : 0;
    u32 incl = v;
#pragma unroll
    for (int off = 1; off < 64; off <<= 1) {
        u32 u = __shfl_up(incl, off, 64);
        if (lane >= off) incl += u;
    }
    if (lane < NCHUNK) G[b * NCHUNK + lane] = bbase[b] + incl - v;
}

// k3: scatter into bucket-grouped order; writes are per-(block,bucket) contiguous runs
__global__ __launch_bounds__(1024) void scatterB_k(const int* __restrict__ rows,
                                                   const int* __restrict__ cols,
                                                   const float* __restrict__ vals,
                                                   const u32* __restrict__ G,
                                                   u32* __restrict__ epack,
                                                   u8* __restrict__ lrow) {
    __shared__ u32 cur[NB];
    int tid = threadIdx.x;
    if (tid < NB) cur[tid] = G[tid * NCHUNK + blockIdx.x];
    __syncthreads();
    int base = blockIdx.x * CHUNK;
    int end = base + CHUNK; if (end > N_EDGES) end = N_EDGES;
    for (int e = base + tid; e < end; e += 1024) {
        int r = rows[e];
        unsigned short vb = __builtin_bit_cast(unsigned short, (bf16)vals[e]);
        u32 pk = ((u32)cols[e] << 16) | (u32)vb;
        u32 p = atomicAdd(&cur[r >> 8], 1);
        epack[p] = pk;
        lrow[p] = (u8)(r & 255);
    }
}

// k4: in-LDS counting sort within each bucket (256 rows); writes starts[], sorted epack
__global__ __launch_bounds__(256) void sortC_k(u32* __restrict__ epack,
                                               const u8* __restrict__ lrow,
                                               const u32* __restrict__ bbase,
                                               int* __restrict__ starts) {
    __shared__ u32 edat[BCAP];
    __shared__ u32 sdat[BCAP];
    __shared__ u8  erow[BCAP];
    __shared__ u32 h[4 * 256];
    __shared__ u32 cur[256];
    __shared__ u32 wtot[4];
    int b = blockIdx.x, tid = threadIdx.x, wid = tid >> 6, lane = tid & 63;
    int s = bbase[b];
    int n = bbase[b + 1] - s;
    if (n > BCAP) n = BCAP;   // cannot trigger for this input; guards LDS
    // load segment
    for (int i = tid; i < n; i += 256) { edat[i] = epack[s + i]; erow[i] = lrow[s + i]; }
    for (int i = tid; i < 1024; i += 256) h[i] = 0;
    __syncthreads();
    // histogram by local row, per-wave
    for (int i = tid; i < n; i += 256) atomicAdd(&h[wid * 256 + erow[i]], 1);
    __syncthreads();
    u32 tot = h[tid] + h[256 + tid] + h[512 + tid] + h[768 + tid];
    u32 incl = tot;
#pragma unroll
    for (int off = 1; off < 64; off <<= 1) {
        u32 u = __shfl_up(incl, off, 64);
        if (lane >= off) incl += u;
    }
    if (lane == 63) wtot[wid] = incl;
    __syncthreads();
    u32 wpre = 0;
#pragma unroll
    for (int w = 0; w < 4; w++)
        if (w < wid) wpre += wtot[w];
    u32 excl = wpre + incl - tot;
    cur[tid] = excl;
    int grow = b * 256 + tid;
    if (grow < N_NODES) starts[grow] = s + (int)excl;
    __syncthreads();
    // place
    for (int i = tid; i < n; i += 256) {
        u32 p = atomicAdd(&cur[erow[i]], 1);
        sdat[p] = edat[i];
    }
    __syncthreads();
    // coalesced dump
    for (int i = tid; i < n; i += 256) epack[s + i] = sdat[i];
}

// ---------------- dtype prep ----------------

__global__ __launch_bounds__(256) void cvt_nf_k(const float* __restrict__ nf,
                                                bf16* __restrict__ a16) {
    size_t gid = (size_t)blockIdx.x * 256 + threadIdx.x;
    const f32x4* s = (const f32x4*)nf;
    f32x4 u = s[gid * 2], v = s[gid * 2 + 1];
    bf16x8 o;
    o[0] = (bf16)u[0]; o[1] = (bf16)u[1]; o[2] = (bf16)u[2]; o[3] = (bf16)u[3];
    o[4] = (bf16)v[0]; o[5] = (bf16)v[1]; o[6] = (bf16)v[2]; o[7] = (bf16)v[3];
    *(bf16x8*)(a16 + gid * 8) = o;
}

__global__ __launch_bounds__(256) void tr_w1_k(const float* __restrict__ W,
                                               bf16* __restrict__ Wt) {
    int i = blockIdx.x * 256 + threadIdx.x;
    int k = i >> 8, n = i & 255;
    Wt[n * F_IN + k] = (bf16)W[i];
}

__global__ __launch_bounds__(256) void tr_w2_k(const float* __restrict__ W,
                                               bf16* __restrict__ Wt) {
    int i = blockIdx.x * 256 + threadIdx.x;
    int k = i >> 6, n = i & 63;
    Wt[n * H_DIM + k] = (bf16)W[i];
}

// ---------------- bf16 MFMA GEMM: C[M,N] = A[M,K] @ Bt[N,K]^T + bias ----------------

template <int BN, bool BF16OUT>
__global__ __launch_bounds__(256) void gemm_k(const bf16* __restrict__ A,
                                              const bf16* __restrict__ Bt,
                                              const float* __restrict__ bias,
                                              void* __restrict__ C,
                                              int M, int K, int Nc) {
    constexpr int BM = 128, BK = 64;
    constexpr int NFRAG = BN / 32;
    constexpr int A_ISS = (BM * BK * 2) / 4096;
    constexpr int B_ISS = (BN * BK * 2) / 4096;
    __shared__ bf16 As[BM * BK];
    __shared__ bf16 Bs[BN * BK];

    int tid = threadIdx.x;
    int wid = tid >> 6, lane = tid & 63;
    int wr = wid >> 1, wc = wid & 1;
    int bm = blockIdx.x, bn = blockIdx.y;

    f32x4 acc[4][NFRAG];
#pragma unroll
    for (int m = 0; m < 4; m++)
#pragma unroll
        for (int n = 0; n < NFRAG; n++) acc[m][n] = (f32x4){0.f, 0.f, 0.f, 0.f};

    for (int kt = 0; kt < K; kt += BK) {
#pragma unroll
        for (int j = 0; j < A_ISS; j++) {
            int chunk = j * 256 + tid;
            int row = chunk >> 3, kc = chunk & 7;
            gl_lds16(A + (size_t)(bm * BM + row) * K + kt + kc * 8,
                     &As[(j * 256 + wid * 64) * 8]);
        }
#pragma unroll
        for (int j = 0; j < B_ISS; j++) {
            int chunk = j * 256 + tid;
            int row = chunk >> 3, kc = chunk & 7;
            gl_lds16(Bt + (size_t)(bn * BN + row) * K + kt + kc * 8,
                     &Bs[(j * 256 + wid * 64) * 8]);
        }
        __syncthreads();

        bf16x8 afr[2][4], bfr[2][NFRAG];
#pragma unroll
        for (int kk = 0; kk < 2; kk++) {
#pragma unroll
            for (int m = 0; m < 4; m++)
                afr[kk][m] = *(const bf16x8*)&As[(wr * 64 + m * 16 + (lane & 15)) * BK +
                                                 kk * 32 + (lane >> 4) * 8];
#pragma unroll
            for (int n = 0; n < NFRAG; n++)
                bfr[kk][n] = *(const bf16x8*)&Bs[(wc * (BN / 2) + n * 16 + (lane & 15)) * BK +
                                                 kk * 32 + (lane >> 4) * 8];
        }
#pragma unroll
        for (int kk = 0; kk < 2; kk++)
#pragma unroll
            for (int m = 0; m < 4; m++)
#pragma unroll
                for (int n = 0; n < NFRAG; n++)
                    acc[m][n] = __builtin_amdgcn_mfma_f32_16x16x32_bf16(
                        afr[kk][m], bfr[kk][n], acc[m][n], 0, 0, 0);
        __syncthreads();
    }

#pragma unroll
    for (int m = 0; m < 4; m++) {
        int row0 = bm * BM + wr * 64 + m * 16 + (lane >> 4) * 4;
#pragma unroll
        for (int n = 0; n < NFRAG; n++) {
            int col = bn * BN + wc * (BN / 2) + n * 16 + (lane & 15);
            float bz = bias[col];
#pragma unroll
            for (int r = 0; r < 4; r++) {
                int row = row0 + r;
                if (row < M) {
                    float v = acc[m][n][r] + bz;
                    if constexpr (BF16OUT)
                        ((bf16*)C)[(size_t)row * Nc + col] = (bf16)v;
                    else
                        ((float*)C)[(size_t)row * Nc + col] = v;
                }
            }
        }
    }
}

// ---------------- SpMM1: x[i,:] = relu(sum val * s1[col,:]), D=256, bf16, unroll 4 ----------------

__global__ __launch_bounds__(256) void spmm1_k(const int* __restrict__ starts,
                                               const u32* __restrict__ epack,
                                               const bf16* __restrict__ s1,
                                               bf16* __restrict__ x16) {
    int wid = threadIdx.x >> 6, lane = threadIdx.x & 63;
    int row = blockIdx.x * 4 + wid;
    if (row >= N_NODES) return;
    int s = starts[row], e = starts[row + 1];
    f32x4 acc = (f32x4){0.f, 0.f, 0.f, 0.f};
    int p = s;
    for (; p + 4 <= e; p += 4) {
        u32 k0 = epack[p], k1 = epack[p + 1], k2 = epack[p + 2], k3 = epack[p + 3];
        float v0 = unpack_val(k0), v1 = unpack_val(k1),
              v2 = unpack_val(k2), v3 = unpack_val(k3);
        bf16x4 g0 = *(const bf16x4*)(s1 + (size_t)(k0 >> 16) * H_DIM + lane * 4);
        bf16x4 g1 = *(const bf16x4*)(s1 + (size_t)(k1 >> 16) * H_DIM + lane * 4);
        bf16x4 g2 = *(const bf16x4*)(s1 + (size_t)(k2 >> 16) * H_DIM + lane * 4);
        bf16x4 g3 = *(const bf16x4*)(s1 + (size_t)(k3 >> 16) * H_DIM + lane * 4);
#pragma unroll
        for (int j = 0; j < 4; j++)
            acc[j] += v0 * (float)g0[j] + v1 * (float)g1[j] +
                      v2 * (float)g2[j] + v3 * (float)g3[j];
    }
    for (; p < e; ++p) {
        u32 k = epack[p];
        float v = unpack_val(k);
        bf16x4 g = *(const bf16x4*)(s1 + (size_t)(k >> 16) * H_DIM + lane * 4);
#pragma unroll
        for (int j = 0; j < 4; j++) acc[j] += v * (float)g[j];
    }
    bf16x4 o;
#pragma unroll
    for (int j = 0; j < 4; j++) o[j] = (bf16)fmaxf(acc[j], 0.f);
    *(bf16x4*)(x16 + (size_t)row * H_DIM + lane * 4) = o;
}

// ---------------- SpMM2 + log_softmax fused: D=64, lane = class, unroll 4 ----------------

__global__ __launch_bounds__(256) void spmm2_sm_k(const int* __restrict__ starts,
                                                  const u32* __restrict__ epack,
                                                  const float* __restrict__ s2,
                                                  float* __restrict__ out) {
    int wid = threadIdx.x >> 6, lane = threadIdx.x & 63;
    int row = blockIdx.x * 4 + wid;
    if (row >= N_NODES) return;
    int s = starts[row], e = starts[row + 1];
    float acc = 0.f;
    int p = s;
    for (; p + 4 <= e; p += 4) {
        u32 k0 = epack[p], k1 = epack[p + 1], k2 = epack[p + 2], k3 = epack[p + 3];
        float g0 = s2[(size_t)(k0 >> 16) * C_DIM + lane];
        float g1 = s2[(size_t)(k1 >> 16) * C_DIM + lane];
        float g2 = s2[(size_t)(k2 >> 16) * C_DIM + lane];
        float g3 = s2[(size_t)(k3 >> 16) * C_DIM + lane];
        acc += unpack_val(k0) * g0 + unpack_val(k1) * g1 +
               unpack_val(k2) * g2 + unpack_val(k3) * g3;
    }
    for (; p < e; ++p) {
        u32 k = epack[p];
        acc += unpack_val(k) * s2[(size_t)(k >> 16) * C_DIM + lane];
    }
    float mx = acc;
#pragma unroll
    for (int off = 32; off >= 1; off >>= 1) mx = fmaxf(mx, __shfl_xor(mx, off, 64));
    float ex = expf(acc - mx);
    float se = ex;
#pragma unroll
    for (int off = 32; off >= 1; off >>= 1) se += __shfl_xor(se, off, 64);
    out[(size_t)row * C_DIM + lane] = (acc - mx) - logf(se);
}

// ---------------- launch ----------------

extern "C" void kernel_launch(void* const* d_in, const int* in_sizes, int n_in,
                              void* d_out, int out_size, void* d_ws, size_t ws_size,
                              hipStream_t stream) {
    const float* nf   = (const float*)d_in[0];
    const int*   rows = (const int*)d_in[1];
    const int*   cols = (const int*)d_in[2];
    const float* vals = (const float*)d_in[3];
    const float* W1   = (const float*)d_in[4];
    const float* b1   = (const float*)d_in[5];
    const float* W2   = (const float*)d_in[6];
    const float* b2   = (const float*)d_in[7];
    float* out = (float*)d_out;

    char* w = (char*)d_ws;
    auto alloc = [&](size_t b) { void* p = (void*)w; w += (b + 255) & ~(size_t)255; return p; };

    bf16* A16 = (bf16*)alloc((size_t)MPAD * F_IN * 2);
    bf16* x16 = A16;
    bf16*  sup1 = (bf16*)alloc((size_t)N_NODES * H_DIM * 2);
    float* sup2 = (float*)sup1;
    bf16* W1t = (bf16*)alloc((size_t)H_DIM * F_IN * 2);
    bf16* W2t = (bf16*)alloc((size_t)C_DIM * H_DIM * 2);
    int* starts = (int*)alloc((size_t)(N_NODES + 1) * 4);
    u32* G      = (u32*)alloc((size_t)NB * NCHUNK * 4);
    u32* bbase  = (u32*)alloc((size_t)(NB + 1) * 4);
    u32* epack  = (u32*)alloc((size_t)N_EDGES * 4);
    u8*  lrow   = (u8*)alloc((size_t)N_EDGES);

    // edge sort (two-level counting sort, coalesced writes)
    histA_k<<<NCHUNK, 1024, 0, stream>>>(rows, G);
    bucket_scan_k<<<1, 256, 0, stream>>>(G, bbase, starts);
    chunk_scan_k<<<NB, 64, 0, stream>>>(G, bbase);
    scatterB_k<<<NCHUNK, 1024, 0, stream>>>(rows, cols, vals, G, epack, lrow);
    sortC_k<<<NB, 256, 0, stream>>>(epack, lrow, bbase, starts);

    // dtype prep
    cvt_nf_k<<<(N_NODES * F_IN / 8) / 256, 256, 0, stream>>>(nf, A16);
    tr_w1_k<<<(F_IN * H_DIM) / 256, 256, 0, stream>>>(W1, W1t);
    tr_w2_k<<<(H_DIM * C_DIM) / 256, 256, 0, stream>>>(W2, W2t);

    // layer 1
    gemm_k<128, true><<<dim3(MPAD / 128, H_DIM / 128), 256, 0, stream>>>(
        A16, W1t, b1, (void*)sup1, N_NODES, F_IN, H_DIM);
    spmm1_k<<<(N_NODES + 3) / 4, 256, 0, stream>>>(starts, epack, sup1, x16);

    // layer 2 + softmax
    gemm_k<64, false><<<dim3(MPAD / 128, 1), 256, 0, stream>>>(
        x16, W2t, b2, (void*)sup2, N_NODES, H_DIM, C_DIM);
    spmm2_sm_k<<<(N_NODES + 3) / 4, 256, 0, stream>>>(starts, epack, sup2, out);

    (void)in_sizes; (void)n_in; (void)out_size; (void)ws_size;
}

// Round 5
// 193.454 us; speedup vs baseline: 1.4400x; 1.1568x over previous
//
#include <hip/hip_runtime.h>

#define N_NODES 50000
#define N_EDGES 800000
#define F_IN    512
#define H_DIM   256
#define C_DIM   64
#define MPAD    50048   // 391 * 128

// sort geometry: bucket = row >> 8 (256 rows/bucket), chunk = 16384 edges
#define NB      196
#define NCHUNK  49
#define CHUNK   16384
#define BCAP    6144

typedef __bf16 bf16;
typedef __bf16 bf16x4 __attribute__((ext_vector_type(4)));
typedef __bf16 bf16x8 __attribute__((ext_vector_type(8)));
typedef float  f32x4  __attribute__((ext_vector_type(4)));
typedef unsigned int u32;
typedef unsigned char u8;

__device__ __forceinline__ void gl_lds16(const void* g, void* l) {
    __builtin_amdgcn_global_load_lds(
        (const __attribute__((address_space(1))) u32*)g,
        (__attribute__((address_space(3))) u32*)l, 16, 0, 0);
}

__device__ __forceinline__ float unpack_val(u32 pk) {
    return __builtin_bit_cast(float, pk << 16);
}

// ---------------- edge sort: two-level counting sort, coalesced writes ----------------

__global__ __launch_bounds__(1024) void histA_k(const int* __restrict__ rows,
                                                u32* __restrict__ G) {
    __shared__ u32 h[16 * NB];
    int tid = threadIdx.x, wid = tid >> 6;
    for (int i = tid; i < 16 * NB; i += 1024) h[i] = 0;
    __syncthreads();
    int base = blockIdx.x * CHUNK;
    int end = base + CHUNK; if (end > N_EDGES) end = N_EDGES;
    for (int e = base + tid; e < end; e += 1024)
        atomicAdd(&h[wid * NB + (rows[e] >> 8)], 1);
    __syncthreads();
    if (tid < NB) {
        u32 s = 0;
#pragma unroll
        for (int w = 0; w < 16; w++) s += h[w * NB + tid];
        G[tid * NCHUNK + blockIdx.x] = s;
    }
}

__global__ __launch_bounds__(256) void bucket_scan_k(const u32* __restrict__ G,
                                                     u32* __restrict__ bbase,
                                                     int* __restrict__ starts) {
    __shared__ u32 wtot[4];
    int tid = threadIdx.x, wid = tid >> 6, lane = tid & 63;
    u32 tot = 0;
    if (tid < NB) {
#pragma unroll
        for (int c = 0; c < NCHUNK; c++) tot += G[tid * NCHUNK + c];
    }
    u32 incl = tot;
#pragma unroll
    for (int off = 1; off < 64; off <<= 1) {
        u32 u = __shfl_up(incl, off, 64);
        if (lane >= off) incl += u;
    }
    if (lane == 63) wtot[wid] = incl;
    __syncthreads();
    u32 wpre = 0;
#pragma unroll
    for (int w = 0; w < 4; w++)
        if (w < wid) wpre += wtot[w];
    if (tid < NB) bbase[tid] = wpre + incl - tot;
    if (tid == 0) { bbase[NB] = N_EDGES; starts[N_NODES] = N_EDGES; }
}

__global__ __launch_bounds__(64) void chunk_scan_k(u32* __restrict__ G,
                                                   const u32* __restrict__ bbase) {
    int b = blockIdx.x, lane = threadIdx.x;
    u32 v = (lane < NCHUNK) ? G[b * NCHUNK + lane] : 0;
    u32 incl = v;
#pragma unroll
    for (int off = 1; off < 64; off <<= 1) {
        u32 u = __shfl_up(incl, off, 64);
        if (lane >= off) incl += u;
    }
    if (lane < NCHUNK) G[b * NCHUNK + lane] = bbase[b] + incl - v;
}

__global__ __launch_bounds__(1024) void scatterB_k(const int* __restrict__ rows,
                                                   const int* __restrict__ cols,
                                                   const float* __restrict__ vals,
                                                   const u32* __restrict__ G,
                                                   u32* __restrict__ epack,
                                                   u8* __restrict__ lrow) {
    __shared__ u32 cur[NB];
    int tid = threadIdx.x;
    if (tid < NB) cur[tid] = G[tid * NCHUNK + blockIdx.x];
    __syncthreads();
    int base = blockIdx.x * CHUNK;
    int end = base + CHUNK; if (end > N_EDGES) end = N_EDGES;
    for (int e = base + tid; e < end; e += 1024) {
        int r = rows[e];
        unsigned short vb = __builtin_bit_cast(unsigned short, (bf16)vals[e]);
        u32 pk = ((u32)cols[e] << 16) | (u32)vb;
        u32 p = atomicAdd(&cur[r >> 8], 1);
        epack[p] = pk;
        lrow[p] = (u8)(r & 255);
    }
}

__global__ __launch_bounds__(256) void sortC_k(u32* __restrict__ epack,
                                               const u8* __restrict__ lrow,
                                               const u32* __restrict__ bbase,
                                               int* __restrict__ starts) {
    __shared__ u32 edat[BCAP];
    __shared__ u32 sdat[BCAP];
    __shared__ u8  erow[BCAP];
    __shared__ u32 h[4 * 256];
    __shared__ u32 cur[256];
    __shared__ u32 wtot[4];
    int b = blockIdx.x, tid = threadIdx.x, wid = tid >> 6, lane = tid & 63;
    int s = bbase[b];
    int n = bbase[b + 1] - s;
    if (n > BCAP) n = BCAP;
    for (int i = tid; i < n; i += 256) { edat[i] = epack[s + i]; erow[i] = lrow[s + i]; }
    for (int i = tid; i < 1024; i += 256) h[i] = 0;
    __syncthreads();
    for (int i = tid; i < n; i += 256) atomicAdd(&h[wid * 256 + erow[i]], 1);
    __syncthreads();
    u32 tot = h[tid] + h[256 + tid] + h[512 + tid] + h[768 + tid];
    u32 incl = tot;
#pragma unroll
    for (int off = 1; off < 64; off <<= 1) {
        u32 u = __shfl_up(incl, off, 64);
        if (lane >= off) incl += u;
    }
    if (lane == 63) wtot[wid] = incl;
    __syncthreads();
    u32 wpre = 0;
#pragma unroll
    for (int w = 0; w < 4; w++)
        if (w < wid) wpre += wtot[w];
    u32 excl = wpre + incl - tot;
    cur[tid] = excl;
    int grow = b * 256 + tid;
    if (grow < N_NODES) starts[grow] = s + (int)excl;
    __syncthreads();
    for (int i = tid; i < n; i += 256) {
        u32 p = atomicAdd(&cur[erow[i]], 1);
        sdat[p] = edat[i];
    }
    __syncthreads();
    for (int i = tid; i < n; i += 256) epack[s + i] = sdat[i];
}

// ---------------- weight prep ----------------

__global__ __launch_bounds__(256) void tr_w1_k(const float* __restrict__ W,
                                               bf16* __restrict__ Wt) {
    int i = blockIdx.x * 256 + threadIdx.x;
    int k = i >> 8, n = i & 255;
    Wt[n * F_IN + k] = (bf16)W[i];
}

__global__ __launch_bounds__(256) void tr_w2_k(const float* __restrict__ W,
                                               bf16* __restrict__ Wt) {
    int i = blockIdx.x * 256 + threadIdx.x;
    int k = i >> 6, n = i & 63;
    Wt[n * H_DIM + k] = (bf16)W[i];
}

// ---------------- GEMM1 fused: C[M,256] = bf16(A_f32[M,512]) @ W1t^T + b1 ----------------
// 8 waves (2x4), BM=128, BN=256, BK=64. A reg-staged f32->bf16; B via global_load_lds.

__global__ __launch_bounds__(512) void gemm1_k(const float* __restrict__ A,
                                               const bf16* __restrict__ Bt,
                                               const float* __restrict__ bias,
                                               bf16* __restrict__ C) {
    constexpr int BM = 128, BN = 256, BK = 64;
    __shared__ bf16 As[BM * BK];
    __shared__ bf16 Bs[BN * BK];

    int tid = threadIdx.x;
    int wid = tid >> 6, lane = tid & 63;
    int wr = wid >> 2, wc = wid & 3;       // 2 x 4 waves, each 64x64 output
    int bm = blockIdx.x;

    f32x4 acc[4][4];
#pragma unroll
    for (int m = 0; m < 4; m++)
#pragma unroll
        for (int n = 0; n < 4; n++) acc[m][n] = (f32x4){0.f, 0.f, 0.f, 0.f};

    for (int kt = 0; kt < F_IN; kt += BK) {
        // B tile: 256 rows x 64 cols bf16 = 32 KB, 4 x gl_lds16 per thread
#pragma unroll
        for (int j = 0; j < 4; j++) {
            int ch = j * 512 + tid;
            int row = ch >> 3, kc = ch & 7;
            gl_lds16(Bt + (size_t)row * F_IN + kt + kc * 8,
                     &Bs[(j * 512 + wid * 64) * 8]);
        }
        // A tile: 128 rows x 64 f32, reg-staged + converted; 2 x (f32x8 -> bf16x8)
#pragma unroll
        for (int j = 0; j < 2; j++) {
            int ch = j * 512 + tid;
            int row = ch >> 3, kc = ch & 7;
            int ar = bm * BM + row;
            if (ar >= N_NODES) ar = N_NODES - 1;   // clamp OOB reads into input
            const f32x4* src = (const f32x4*)(A + (size_t)ar * F_IN + kt + kc * 8);
            f32x4 u = src[0], v = src[1];
            bf16x8 o;
            o[0] = (bf16)u[0]; o[1] = (bf16)u[1]; o[2] = (bf16)u[2]; o[3] = (bf16)u[3];
            o[4] = (bf16)v[0]; o[5] = (bf16)v[1]; o[6] = (bf16)v[2]; o[7] = (bf16)v[3];
            *(bf16x8*)&As[(size_t)ch * 8] = o;
        }
        __syncthreads();

        bf16x8 afr[2][4], bfr[2][4];
#pragma unroll
        for (int kk = 0; kk < 2; kk++) {
#pragma unroll
            for (int m = 0; m < 4; m++)
                afr[kk][m] = *(const bf16x8*)&As[(wr * 64 + m * 16 + (lane & 15)) * BK +
                                                 kk * 32 + (lane >> 4) * 8];
#pragma unroll
            for (int n = 0; n < 4; n++)
                bfr[kk][n] = *(const bf16x8*)&Bs[(wc * 64 + n * 16 + (lane & 15)) * BK +
                                                 kk * 32 + (lane >> 4) * 8];
        }
#pragma unroll
        for (int kk = 0; kk < 2; kk++)
#pragma unroll
            for (int m = 0; m < 4; m++)
#pragma unroll
                for (int n = 0; n < 4; n++)
                    acc[m][n] = __builtin_amdgcn_mfma_f32_16x16x32_bf16(
                        afr[kk][m], bfr[kk][n], acc[m][n], 0, 0, 0);
        __syncthreads();
    }

#pragma unroll
    for (int m = 0; m < 4; m++) {
        int row0 = bm * BM + wr * 64 + m * 16 + (lane >> 4) * 4;
#pragma unroll
        for (int n = 0; n < 4; n++) {
            int col = wc * 64 + n * 16 + (lane & 15);
            float bz = bias[col];
#pragma unroll
            for (int r = 0; r < 4; r++) {
                int row = row0 + r;
                if (row < N_NODES)
                    C[(size_t)row * H_DIM + col] = (bf16)(acc[m][n][r] + bz);
            }
        }
    }
}

// ---------------- GEMM2: C[M,64] = x16[M,256] @ W2t^T + b2 (bf16 in/out) ----------------

__global__ __launch_bounds__(256) void gemm2_k(const bf16* __restrict__ A,
                                               const bf16* __restrict__ Bt,
                                               const float* __restrict__ bias,
                                               bf16* __restrict__ C) {
    constexpr int BM = 128, BN = 64, BK = 64;
    __shared__ bf16 As[BM * BK];
    __shared__ bf16 Bs[BN * BK];

    int tid = threadIdx.x;
    int wid = tid >> 6, lane = tid & 63;
    int wr = wid >> 1, wc = wid & 1;
    int bm = blockIdx.x;

    f32x4 acc[4][2];
#pragma unroll
    for (int m = 0; m < 4; m++)
#pragma unroll
        for (int n = 0; n < 2; n++) acc[m][n] = (f32x4){0.f, 0.f, 0.f, 0.f};

    for (int kt = 0; kt < H_DIM; kt += BK) {
#pragma unroll
        for (int j = 0; j < 4; j++) {
            int ch = j * 256 + tid;
            int row = ch >> 3, kc = ch & 7;
            gl_lds16(A + (size_t)(bm * BM + row) * H_DIM + kt + kc * 8,
                     &As[(j * 256 + wid * 64) * 8]);
        }
#pragma unroll
        for (int j = 0; j < 2; j++) {
            int ch = j * 256 + tid;
            int row = ch >> 3, kc = ch & 7;
            gl_lds16(Bt + (size_t)row * H_DIM + kt + kc * 8,
                     &Bs[(j * 256 + wid * 64) * 8]);
        }
        __syncthreads();

        bf16x8 afr[2][4], bfr[2][2];
#pragma unroll
        for (int kk = 0; kk < 2; kk++) {
#pragma unroll
            for (int m = 0; m < 4; m++)
                afr[kk][m] = *(const bf16x8*)&As[(wr * 64 + m * 16 + (lane & 15)) * BK +
                                                 kk * 32 + (lane >> 4) * 8];
#pragma unroll
            for (int n = 0; n < 2; n++)
                bfr[kk][n] = *(const bf16x8*)&Bs[(wc * 32 + n * 16 + (lane & 15)) * BK +
                                                 kk * 32 + (lane >> 4) * 8];
        }
#pragma unroll
        for (int kk = 0; kk < 2; kk++)
#pragma unroll
            for (int m = 0; m < 4; m++)
#pragma unroll
                for (int n = 0; n < 2; n++)
                    acc[m][n] = __builtin_amdgcn_mfma_f32_16x16x32_bf16(
                        afr[kk][m], bfr[kk][n], acc[m][n], 0, 0, 0);
        __syncthreads();
    }

#pragma unroll
    for (int m = 0; m < 4; m++) {
        int row0 = bm * BM + wr * 64 + m * 16 + (lane >> 4) * 4;
#pragma unroll
        for (int n = 0; n < 2; n++) {
            int col = wc * 32 + n * 16 + (lane & 15);
            float bz = bias[col];
#pragma unroll
            for (int r = 0; r < 4; r++) {
                int row = row0 + r;
                if (row < N_NODES)
                    C[(size_t)row * C_DIM + col] = (bf16)(acc[m][n][r] + bz);
            }
        }
    }
}

// ---------------- SpMM1: x[i,:] = relu(sum val * s1[col,:]), D=256, bf16, unroll 4 ----------------

__global__ __launch_bounds__(256) void spmm1_k(const int* __restrict__ starts,
                                               const u32* __restrict__ epack,
                                               const bf16* __restrict__ s1,
                                               bf16* __restrict__ x16) {
    int wid = threadIdx.x >> 6, lane = threadIdx.x & 63;
    int row = blockIdx.x * 4 + wid;
    if (row >= N_NODES) return;
    int s = starts[row], e = starts[row + 1];
    f32x4 acc = (f32x4){0.f, 0.f, 0.f, 0.f};
    int p = s;
    for (; p + 4 <= e; p += 4) {
        u32 k0 = epack[p], k1 = epack[p + 1], k2 = epack[p + 2], k3 = epack[p + 3];
        float v0 = unpack_val(k0), v1 = unpack_val(k1),
              v2 = unpack_val(k2), v3 = unpack_val(k3);
        bf16x4 g0 = *(const bf16x4*)(s1 + (size_t)(k0 >> 16) * H_DIM + lane * 4);
        bf16x4 g1 = *(const bf16x4*)(s1 + (size_t)(k1 >> 16) * H_DIM + lane * 4);
        bf16x4 g2 = *(const bf16x4*)(s1 + (size_t)(k2 >> 16) * H_DIM + lane * 4);
        bf16x4 g3 = *(const bf16x4*)(s1 + (size_t)(k3 >> 16) * H_DIM + lane * 4);
#pragma unroll
        for (int j = 0; j < 4; j++)
            acc[j] += v0 * (float)g0[j] + v1 * (float)g1[j] +
                      v2 * (float)g2[j] + v3 * (float)g3[j];
    }
    for (; p < e; ++p) {
        u32 k = epack[p];
        float v = unpack_val(k);
        bf16x4 g = *(const bf16x4*)(s1 + (size_t)(k >> 16) * H_DIM + lane * 4);
#pragma unroll
        for (int j = 0; j < 4; j++) acc[j] += v * (float)g[j];
    }
    bf16x4 o;
#pragma unroll
    for (int j = 0; j < 4; j++) o[j] = (bf16)fmaxf(acc[j], 0.f);
    *(bf16x4*)(x16 + (size_t)row * H_DIM + lane * 4) = o;
}

// ---------------- SpMM2 + log_softmax fused: D=64, lane = class, bf16 gather ----------------

__global__ __launch_bounds__(256) void spmm2_sm_k(const int* __restrict__ starts,
                                                  const u32* __restrict__ epack,
                                                  const bf16* __restrict__ s2,
                                                  float* __restrict__ out) {
    int wid = threadIdx.x >> 6, lane = threadIdx.x & 63;
    int row = blockIdx.x * 4 + wid;
    if (row >= N_NODES) return;
    int s = starts[row], e = starts[row + 1];
    float acc = 0.f;
    int p = s;
    for (; p + 4 <= e; p += 4) {
        u32 k0 = epack[p], k1 = epack[p + 1], k2 = epack[p + 2], k3 = epack[p + 3];
        float g0 = (float)s2[(size_t)(k0 >> 16) * C_DIM + lane];
        float g1 = (float)s2[(size_t)(k1 >> 16) * C_DIM + lane];
        float g2 = (float)s2[(size_t)(k2 >> 16) * C_DIM + lane];
        float g3 = (float)s2[(size_t)(k3 >> 16) * C_DIM + lane];
        acc += unpack_val(k0) * g0 + unpack_val(k1) * g1 +
               unpack_val(k2) * g2 + unpack_val(k3) * g3;
    }
    for (; p < e; ++p) {
        u32 k = epack[p];
        acc += unpack_val(k) * (float)s2[(size_t)(k >> 16) * C_DIM + lane];
    }
    float mx = acc;
#pragma unroll
    for (int off = 32; off >= 1; off >>= 1) mx = fmaxf(mx, __shfl_xor(mx, off, 64));
    float ex = expf(acc - mx);
    float se = ex;
#pragma unroll
    for (int off = 32; off >= 1; off >>= 1) se += __shfl_xor(se, off, 64);
    out[(size_t)row * C_DIM + lane] = (acc - mx) - logf(se);
}

// ---------------- launch ----------------

extern "C" void kernel_launch(void* const* d_in, const int* in_sizes, int n_in,
                              void* d_out, int out_size, void* d_ws, size_t ws_size,
                              hipStream_t stream) {
    const float* nf   = (const float*)d_in[0];
    const int*   rows = (const int*)d_in[1];
    const int*   cols = (const int*)d_in[2];
    const float* vals = (const float*)d_in[3];
    const float* W1   = (const float*)d_in[4];
    const float* b1   = (const float*)d_in[5];
    const float* W2   = (const float*)d_in[6];
    const float* b2   = (const float*)d_in[7];
    float* out = (float*)d_out;

    char* w = (char*)d_ws;
    auto alloc = [&](size_t b) { void* p = (void*)w; w += (b + 255) & ~(size_t)255; return p; };

    bf16* x16  = (bf16*)alloc((size_t)MPAD * H_DIM * 2);   // spmm1 out / gemm2 in
    bf16* sup1 = (bf16*)alloc((size_t)N_NODES * H_DIM * 2);
    bf16* sup2 = sup1;                                     // aliases sup1 (dead by then)
    bf16* W1t = (bf16*)alloc((size_t)H_DIM * F_IN * 2);
    bf16* W2t = (bf16*)alloc((size_t)C_DIM * H_DIM * 2);
    int* starts = (int*)alloc((size_t)(N_NODES + 1) * 4);
    u32* G      = (u32*)alloc((size_t)NB * NCHUNK * 4);
    u32* bbase  = (u32*)alloc((size_t)(NB + 1) * 4);
    u32* epack  = (u32*)alloc((size_t)N_EDGES * 4);
    u8*  lrow   = (u8*)alloc((size_t)N_EDGES);

    // edge sort (two-level counting sort, coalesced writes)
    histA_k<<<NCHUNK, 1024, 0, stream>>>(rows, G);
    bucket_scan_k<<<1, 256, 0, stream>>>(G, bbase, starts);
    chunk_scan_k<<<NB, 64, 0, stream>>>(G, bbase);
    scatterB_k<<<NCHUNK, 1024, 0, stream>>>(rows, cols, vals, G, epack, lrow);
    sortC_k<<<NB, 256, 0, stream>>>(epack, lrow, bbase, starts);

    // weight prep
    tr_w1_k<<<(F_IN * H_DIM) / 256, 256, 0, stream>>>(W1, W1t);
    tr_w2_k<<<(H_DIM * C_DIM) / 256, 256, 0, stream>>>(W2, W2t);

    // layer 1 (fused f32->bf16 A staging)
    gemm1_k<<<MPAD / 128, 512, 0, stream>>>(nf, W1t, b1, sup1);
    spmm1_k<<<(N_NODES + 3) / 4, 256, 0, stream>>>(starts, epack, sup1, x16);

    // layer 2 + softmax
    gemm2_k<<<MPAD / 128, 256, 0, stream>>>(x16, W2t, b2, sup2);
    spmm2_sm_k<<<(N_NODES + 3) / 4, 256, 0, stream>>>(starts, epack, sup2, out);

    (void)in_sizes; (void)n_in; (void)out_size; (void)ws_size;
}